// Round 2
// baseline (889.404 us; speedup 1.0000x reference)
//
#include <hip/hip_runtime.h>
#include <math.h>

// Boltzmann machine sequential Gibbs sweep, N=8192.
// Per block of B=512 scan positions:
//   k_matvec: Sraw[r] = w[perm[bB+r]] . state  (fp64 accum, state at block start)
//             subM[r][s] = w[perm[bB+r]][perm[bB+s]]  (block coupling tile)
//   k_scan (1 WG): sequential scan of the 512 positions; 8 wave-lockstep
//             64-step sub-scans + rank-64 fp64 updates between them.
// Decision: u <= sigmoid(s/T)  <=>  s >= T*log(u/(1-u))  (thr in fp64).
// NOTE: rand_u is SCAN-POSITION indexed (lax.scan zips (perm, rand_u));
// clamping_degree / state are UNIT indexed.

#define NN 8192
#define BB 512
#define NBLK (NN / BB)   // 16
#define SUB 64
#define NSUB (BB / SUB)  // 8

__global__ __launch_bounds__(256) void k_prep(const float* __restrict__ init,
                                              const float* __restrict__ urand,
                                              const float* __restrict__ Tp,
                                              float* __restrict__ state,
                                              double* __restrict__ thr) {
    int i = blockIdx.x * blockDim.x + threadIdx.x;
    if (i < NN) {
        state[i] = init[i];
        double u = (double)urand[i];
        // u==0 -> thr=-inf -> decision always 1 (matches u<=p).
        thr[i] = (double)Tp[0] * log(u / (1.0 - u));
    }
}

// One workgroup per row of the block. Products w*state are exact in fp32
// (state is 0/1); accumulation in fp64 -> near-exact dot.
__global__ __launch_bounds__(256) void k_matvec(const float* __restrict__ w,
                                                const float* __restrict__ state,
                                                const int* __restrict__ perm,
                                                double* __restrict__ Sraw,
                                                float* __restrict__ subM,
                                                int b) {
    int r = blockIdx.x;      // 0..BB-1 (scan position within block)
    int tid = threadIdx.x;   // 0..255
    int row = perm[b * BB + r];
    const float4* wr = (const float4*)(w + (size_t)row * NN);
    const float4* st = (const float4*)state;
    double acc = 0.0;
#pragma unroll
    for (int k = 0; k < NN / 4 / 256; ++k) {  // 8 iterations
        float4 wv = wr[tid + k * 256];
        float4 sv = st[tid + k * 256];
        acc += (double)(wv.x * sv.x) + (double)(wv.y * sv.y) +
               (double)(wv.z * sv.z) + (double)(wv.w * sv.w);
    }
    __shared__ double red[256];
    red[tid] = acc;
    __syncthreads();
    for (int off = 128; off > 0; off >>= 1) {
        if (tid < off) red[tid] += red[tid + off];
        __syncthreads();
    }
    if (tid == 0) Sraw[r] = red[0];
    // Extract the block coupling tile (row is L1/L2-hot from the stream above).
    for (int s = tid; s < BB; s += 256) {
        int col = perm[b * BB + s];
        subM[(size_t)r * BB + s] = w[(size_t)row * NN + col];
    }
}

// Single workgroup, 1024 threads. Wave 0 runs the lockstep 64-step scans;
// all 16 waves share the rank-64 updates between sub-blocks.
__global__ __launch_bounds__(1024) void k_scan(float* __restrict__ state,
                                               const double* __restrict__ thr,
                                               const float* __restrict__ clampv,
                                               const int* __restrict__ perm,
                                               const double* __restrict__ Sraw,
                                               const float* __restrict__ subM,
                                               int b) {
    int tid = threadIdx.x;
    int lane = tid & 63;
    int wv = tid >> 6;
    __shared__ double sums[BB];
    __shared__ double thrL[BB];
    __shared__ float d1L[BB], d0L[BB], oldL[BB], delL[BB];

    if (tid < BB) {
        int t = tid;
        int unit = perm[b * BB + t];
        sums[t] = Sraw[t];
        thrL[t] = thr[b * BB + t];       // position-indexed (THE FIX)
        float old = state[unit];
        oldL[t] = old;
        bool cl = (clampv[unit] != 0.0f);
        d1L[t] = cl ? 0.0f : (1.0f - old);  // delta if decision==1
        d0L[t] = cl ? 0.0f : (0.0f - old);  // delta if decision==0
    }
    __syncthreads();

    for (int t8 = 0; t8 < NSUB; ++t8) {
        if (wv == 0) {
            int idx = t8 * SUB + lane;
            // lane's row of the diagonal 64x64 tile -> 64 registers
            const float4* mrow = (const float4*)(subM + (size_t)idx * BB + t8 * SUB);
            float m[SUB];
#pragma unroll
            for (int j = 0; j < SUB / 4; ++j) {
                float4 mv = mrow[j];
                m[4 * j] = mv.x; m[4 * j + 1] = mv.y;
                m[4 * j + 2] = mv.z; m[4 * j + 3] = mv.w;
            }
            double sum = sums[idx];
            double th = thrL[idx];
            float d1 = d1L[idx];
            float d0 = d0L[idx];
            float mydelta = 0.0f;
#pragma unroll
            for (int s = 0; s < SUB; ++s) {
                // At step s, lane s's sum is fully corrected; lane s's delta
                // is broadcast, all lanes fold in the exact correction term.
                float down = (sum >= th) ? d1 : d0;
                float sd = __shfl(down, s, 64);
                if (s == lane) mydelta = down;
                sum += (double)(m[s] * sd);   // m*sd exact in fp32
            }
            delL[idx] = mydelta;
        }
        __syncthreads();
        // rank-64 fp64 update of remaining positions in the block
        for (int r = t8 * SUB + SUB + tid; r < BB; r += 1024) {
            const float4* mr = (const float4*)(subM + (size_t)r * BB + t8 * SUB);
            double acc = sums[r];
#pragma unroll
            for (int j = 0; j < SUB / 4; ++j) {
                float4 mv = mr[j];
                acc += (double)(mv.x * delL[t8 * SUB + 4 * j]) +
                       (double)(mv.y * delL[t8 * SUB + 4 * j + 1]) +
                       (double)(mv.z * delL[t8 * SUB + 4 * j + 2]) +
                       (double)(mv.w * delL[t8 * SUB + 4 * j + 3]);
            }
            sums[r] = acc;
        }
        __syncthreads();
    }

    if (tid < BB) {
        int unit = perm[b * BB + tid];
        state[unit] = oldL[tid] + delL[tid];  // exact: values in {0,1}
    }
}

extern "C" void kernel_launch(void* const* d_in, const int* in_sizes, int n_in,
                              void* d_out, int out_size, void* d_ws, size_t ws_size,
                              hipStream_t stream) {
    const float* w      = (const float*)d_in[0];
    const float* init   = (const float*)d_in[1];
    const float* clampv = (const float*)d_in[2];
    const float* Tp     = (const float*)d_in[3];
    const int*   perm   = (const int*)d_in[4];
    const float* urand  = (const float*)d_in[5];

    float* state = (float*)d_out;            // live state == final output
    double* thr  = (double*)d_ws;            // NN doubles
    double* Sraw = thr + NN;                 // BB doubles
    float*  subM = (float*)(Sraw + BB);      // BB*BB floats (~1 MB)

    k_prep<<<NN / 256, 256, 0, stream>>>(init, urand, Tp, state, thr);
    for (int b = 0; b < NBLK; ++b) {
        k_matvec<<<BB, 256, 0, stream>>>(w, state, perm, Sraw, subM, b);
        k_scan<<<1, 1024, 0, stream>>>(state, thr, clampv, perm, Sraw, subM, b);
    }
}